// Round 13
// baseline (87.142 us; speedup 1.0000x reference)
//
#include <hip/hip_runtime.h>

#define D_MODEL 1024
#define HDIM    64
#define BATCH   8
#define SEQ     2048
#define BT      (BATCH*SEQ)
#define NCAT    192
#define KSTEP   32
#define NKS     (D_MODEL/KSTEP)          // 32 k-steps
#define FRAGSH  512                      // shorts per frag: 64 lanes x 8
#define STEPSH  (24*FRAGSH)              // 24 frags (12 hi + 12 lo) per k-step

typedef __attribute__((ext_vector_type(8))) short s8v;
typedef __attribute__((ext_vector_type(4))) float f4;

__device__ __forceinline__ unsigned short f2bf(float f){
    unsigned u = __builtin_bit_cast(unsigned, f);
    u += 0x7fffu + ((u >> 16) & 1u);
    return (unsigned short)(u >> 16);
}
__device__ __forceinline__ float bf2f(unsigned short h){
    unsigned u = ((unsigned)h) << 16;
    return __builtin_bit_cast(float, u);
}
__device__ __forceinline__ f4 MFMA(s8v a, s8v b, f4 c){
    return __builtin_amdgcn_mfma_f32_16x16x32_bf16(a, b, c, 0, 0, 0);
}

// ---- kernel 1: W -> fragment-packed Wt (hi/lo) ----
// wtP layout: [kstep t1][frag f][lane l][e] shorts; f<12: hi of subtile nb=f,
// f>=12: lo of nb=f-12. One frag = 64 lanes x 16B, contiguous 1KB.
__global__ void prep_w_kernel(const float* __restrict__ wq, const float* __restrict__ wk,
                              const float* __restrict__ wv,
                              short* __restrict__ wtP){
    int ncat = blockIdx.x;
    const float* w = (ncat < 64) ? wq : ((ncat < 128) ? wk : wv);
    int n  = ncat & 63;
    int nb = ncat >> 4, ln = ncat & 15;
    for (int k = threadIdx.x; k < D_MODEL; k += blockDim.x){
        float f = w[k*HDIM + n];
        unsigned short h = f2bf(f);
        unsigned short l = f2bf(f - bf2f(h));
        int t1 = k >> 5, g = (k >> 3) & 3, e = k & 7;
        size_t base = (size_t)t1*STEPSH + (size_t)((g*16 + ln) << 3) + e;
        wtP[base + (size_t)nb*FRAGSH]        = (short)h;
        wtP[base + (size_t)(12 + nb)*FRAGSH] = (short)l;
    }
}

// ---- kernel 2: fused QKV projection — barrier-free, LDS-free dataflow ----
// 512 blocks x 4 INDEPENDENT waves (no __syncthreads -> no vmcnt(0) drains;
// compiler emits counted per-reg vmcnt). Each wave: 32 rows x 48 cols.
// x read per-lane direct (rows ln/ln+16, 128B full-line spans), cvt to bf16
// in-reg (hi only; W stays hi/lo). x and W double-buffered 2 k-steps ahead.
// All 4 waves share the same 32 x-rows -> L1 dedups x to ~1x HBM.
__global__ __launch_bounds__(256, 2) void proj_kernel(
        const float* __restrict__ x,
        const short* __restrict__ wtP,
        short* __restrict__ q, short* __restrict__ k,
        short* __restrict__ vt){
    int tid = threadIdx.x;
    int wn = tid >> 6, lane = tid & 63, g = lane >> 4, ln = lane & 15;
    int m0 = blockIdx.x * 32;

    const float* xp0 = x + (size_t)(m0 + ln)*D_MODEL + g*8;
    const float* xp1 = xp0 + (size_t)16*D_MODEL;
    const short* wb  = wtP + (size_t)(wn*3)*FRAGSH + (size_t)lane*8;

    f4 acc[6];
#pragma unroll
    for (int i = 0; i < 6; i++) acc[i] = (f4){0.f,0.f,0.f,0.f};

    float4 xA00, xA01, xA10, xA11, xB00, xB01, xB10, xB11;
    s8v whA0, whA1, whA2, wlA0, wlA1, wlA2;
    s8v whB0, whB1, whB2, wlB0, wlB1, wlB2;

#define LOADX(P, T) { \
    x##P##00 = *(const float4*)(xp0 + (size_t)(T)*KSTEP); \
    x##P##01 = *(const float4*)(xp0 + (size_t)(T)*KSTEP + 4); \
    x##P##10 = *(const float4*)(xp1 + (size_t)(T)*KSTEP); \
    x##P##11 = *(const float4*)(xp1 + (size_t)(T)*KSTEP + 4); }

#define LOADW(P, T) { \
    const short* wp = wb + (size_t)(T)*STEPSH; \
    wh##P##0 = *(const s8v*)(wp); \
    wh##P##1 = *(const s8v*)(wp + FRAGSH); \
    wh##P##2 = *(const s8v*)(wp + 2*FRAGSH); \
    wl##P##0 = *(const s8v*)(wp + 12*FRAGSH); \
    wl##P##1 = *(const s8v*)(wp + 13*FRAGSH); \
    wl##P##2 = *(const s8v*)(wp + 14*FRAGSH); }

#define CVT8(DST, VA, VB) { \
    DST[0] = (short)f2bf(VA.x); DST[1] = (short)f2bf(VA.y); \
    DST[2] = (short)f2bf(VA.z); DST[3] = (short)f2bf(VA.w); \
    DST[4] = (short)f2bf(VB.x); DST[5] = (short)f2bf(VB.y); \
    DST[6] = (short)f2bf(VB.z); DST[7] = (short)f2bf(VB.w); }

#define MFMAS(P, A0, A1) { \
    acc[0] = MFMA(A0, wh##P##0, acc[0]); acc[0] = MFMA(A0, wl##P##0, acc[0]); \
    acc[1] = MFMA(A0, wh##P##1, acc[1]); acc[1] = MFMA(A0, wl##P##1, acc[1]); \
    acc[2] = MFMA(A0, wh##P##2, acc[2]); acc[2] = MFMA(A0, wl##P##2, acc[2]); \
    acc[3] = MFMA(A1, wh##P##0, acc[3]); acc[3] = MFMA(A1, wl##P##0, acc[3]); \
    acc[4] = MFMA(A1, wh##P##1, acc[4]); acc[4] = MFMA(A1, wl##P##1, acc[4]); \
    acc[5] = MFMA(A1, wh##P##2, acc[5]); acc[5] = MFMA(A1, wl##P##2, acc[5]); }

    // prologue: steps 0 and 1 in flight
    LOADX(A, 0)
    LOADX(B, 1)
    LOADW(A, 0)
    LOADW(B, 1)

    for (int t = 0; t + 2 < NKS; t += 2){
        s8v aA0, aA1, aB0, aB1;
        // step t (buffer A)
        CVT8(aA0, xA00, xA01)       // waits only on xA (issued 2 steps ago)
        CVT8(aA1, xA10, xA11)
        LOADX(A, t + 2)             // refill A x-regs (anti-dep after CVT)
        MFMAS(A, aA0, aA1)          // waits on WA (issued 2 steps ago)
        LOADW(A, t + 2)             // refill A W-regs
        // step t+1 (buffer B)
        CVT8(aB0, xB00, xB01)
        CVT8(aB1, xB10, xB11)
        LOADX(B, t + 3)
        MFMAS(B, aB0, aB1)
        LOADW(B, t + 3)
    }
    {   // tail: steps 30, 31
        s8v aA0, aA1, aB0, aB1;
        CVT8(aA0, xA00, xA01)
        CVT8(aA1, xA10, xA11)
        MFMAS(A, aA0, aA1)
        CVT8(aB0, xB00, xB01)
        CVT8(aB1, xB10, xB11)
        MFMAS(B, aB0, aB1)
    }
#undef LOADX
#undef LOADW
#undef CVT8
#undef MFMAS

    // epilogue: q,k,v single bf16 (GEMM was x_bf16 * W_fp32-accurate)
#pragma unroll
    for (int rf = 0; rf < 2; rf++){
#pragma unroll
        for (int nb = 0; nb < 3; nb++){
            int ncat = wn*48 + nb*16 + ln;
            int mat = ncat >> 6, h = ncat & 63;
#pragma unroll
            for (int r = 0; r < 4; r++){
                size_t trow = (size_t)m0 + rf*16 + g*4 + r;
                float v = acc[rf*3 + nb][r];
                unsigned short hh = f2bf(v);
                if (mat == 0){
                    q[trow*HDIM + h] = (short)hh;
                } else if (mat == 1){
                    k[trow*HDIM + h] = (short)hh;
                } else {
                    size_t bb = trow >> 11, t2 = trow & 2047;
                    vt[((bb*HDIM + h) << 11) + t2] = (short)hh;
                }
            }
        }
    }
}

// ---- kernel 3: causal flash attention, in-block KV-split, KVBLK=64 ----
// Single-bf16 Q/K; wave w owns KV tiles w, w+4, ...; partials merged in LDS
// at block end (exact algebra). qi swizzle balances per-CU work.
__global__ __launch_bounds__(256, 5) void attn_kernel(
        const short* __restrict__ qg, const short* __restrict__ kg,
        const short* __restrict__ vt, float* __restrict__ out){
    __shared__ unsigned short plds[4][16][112];
    __shared__ float olds[4][16][65];
    __shared__ float mlds[4][16], llds[4][16];
    const float SC = 0.125f * 1.44269504088896340736f;  // 1/sqrt(64) * log2(e)
    int tid = threadIdx.x;
    int w = tid >> 6, lane = tid & 63, g = lane >> 4, ln = lane & 15;
    int b = blockIdx.y;
    int qi = ((blockIdx.y >> 1) & 1) ? (int)(gridDim.x - 1 - blockIdx.x) : (int)blockIdx.x;
    int tq = qi * 16;

    size_t qoff = ((size_t)b*SEQ + tq + ln) * HDIM + g*8;
    s8v q0 = *(const s8v*)(qg + qoff);
    s8v q1 = *(const s8v*)(qg + qoff + 32);

    f4 o0 = {0.f,0.f,0.f,0.f}, o1 = o0, o2 = o0, o3 = o0;
    float m[4], lsum[4];
#pragma unroll
    for (int r = 0; r < 4; r++){ m[r] = -__builtin_inff(); lsum[r] = 0.f; }

    int ntiles = (tq + 79) >> 6;   // ceil((tq+16)/64)
    for (int ti = w; ti < ntiles; ti += 4){
        int s0 = ti << 6;
        size_t kbase = ((size_t)b*SEQ + s0 + ln) * HDIM + g*8;
        f4 z0, z1, z2, z3;
#define QK_SUBTILE(ZJ, J) { \
        const short* kp = kg + kbase + (J)*16*HDIM; \
        s8v k0 = *(const s8v*)(kp); \
        s8v k1 = *(const s8v*)(kp + 32); \
        f4 s = {0.f,0.f,0.f,0.f}; \
        s = MFMA(q0, k0, s); s = MFMA(q1, k1, s); \
        ZJ[0] = s[0]*SC; ZJ[1] = s[1]*SC; ZJ[2] = s[2]*SC; ZJ[3] = s[3]*SC; }
        QK_SUBTILE(z0, 0)
        QK_SUBTILE(z1, 1)
        QK_SUBTILE(z2, 2)
        QK_SUBTILE(z3, 3)
#undef QK_SUBTILE
        if (s0 + 63 > tq){   // causal mask (near-diagonal tiles only)
#pragma unroll
            for (int r = 0; r < 4; r++){
                int t = tq + g*4 + r;
                if (s0      + ln > t) z0[r] = -__builtin_inff();
                if (s0 + 16 + ln > t) z1[r] = -__builtin_inff();
                if (s0 + 32 + ln > t) z2[r] = -__builtin_inff();
                if (s0 + 48 + ln > t) z3[r] = -__builtin_inff();
            }
        }
        float al[4];
#pragma unroll
        for (int r = 0; r < 4; r++){
            float v = fmaxf(fmaxf(z0[r], z1[r]), fmaxf(z2[r], z3[r]));
            v = fmaxf(v, __shfl_xor(v, 1));
            v = fmaxf(v, __shfl_xor(v, 2));
            v = fmaxf(v, __shfl_xor(v, 4));
            v = fmaxf(v, __shfl_xor(v, 8));
            float mn = fmaxf(m[r], v);
            al[r] = __builtin_amdgcn_exp2f(m[r] - mn);
            float p0 = __builtin_amdgcn_exp2f(z0[r] - mn);
            float p1 = __builtin_amdgcn_exp2f(z1[r] - mn);
            float p2 = __builtin_amdgcn_exp2f(z2[r] - mn);
            float p3 = __builtin_amdgcn_exp2f(z3[r] - mn);
            lsum[r] = lsum[r]*al[r] + ((p0 + p1) + (p2 + p3));  // lane-partial
            m[r] = mn;
            int row = g*4 + r;
            plds[w][row][ln]      = f2bf(p0);
            plds[w][row][ln + 16] = f2bf(p1);
            plds[w][row][ln + 32] = f2bf(p2);
            plds[w][row][ln + 48] = f2bf(p3);
        }
#pragma unroll
        for (int r = 0; r < 4; r++){
            o0[r] *= al[r]; o1[r] *= al[r]; o2[r] *= al[r]; o3[r] *= al[r];
        }
        asm volatile("s_waitcnt lgkmcnt(0)" ::: "memory");  // cross-lane P write->read
        __builtin_amdgcn_sched_barrier(0);
        s8v pa0 = *(const s8v*)&plds[w][ln][g*8];
        s8v pa1 = *(const s8v*)&plds[w][ln][32 + g*8];
        size_t voff = ((size_t)b*HDIM + ln) * SEQ + s0 + g*8;
        s8v v00 = *(const s8v*)(vt + voff);
        s8v v01 = *(const s8v*)(vt + voff + 32);
        s8v v10 = *(const s8v*)(vt + voff + 16*SEQ);
        s8v v11 = *(const s8v*)(vt + voff + 16*SEQ + 32);
        s8v v20 = *(const s8v*)(vt + voff + 32*SEQ);
        s8v v21 = *(const s8v*)(vt + voff + 32*SEQ + 32);
        s8v v30 = *(const s8v*)(vt + voff + 48*SEQ);
        s8v v31 = *(const s8v*)(vt + voff + 48*SEQ + 32);
        o0 = MFMA(pa0, v00, o0); o0 = MFMA(pa1, v01, o0);
        o1 = MFMA(pa0, v10, o1); o1 = MFMA(pa1, v11, o1);
        o2 = MFMA(pa0, v20, o2); o2 = MFMA(pa1, v21, o2);
        o3 = MFMA(pa0, v30, o3); o3 = MFMA(pa1, v31, o3);
    }

    // deferred l-sum reduce (off the per-tile critical path)
#pragma unroll
    for (int r = 0; r < 4; r++){
        float s = lsum[r];
        s += __shfl_xor(s, 1);
        s += __shfl_xor(s, 2);
        s += __shfl_xor(s, 4);
        s += __shfl_xor(s, 8);
        lsum[r] = s;
    }

    // ---- write per-wave partials to LDS ----
#pragma unroll
    for (int r = 0; r < 4; r++){
        int row = g*4 + r;
        olds[w][row][ln]      = o0[r];
        olds[w][row][ln + 16] = o1[r];
        olds[w][row][ln + 32] = o2[r];
        olds[w][row][ln + 48] = o3[r];
        if (ln == 0){ mlds[w][row] = m[r]; llds[w][row] = lsum[r]; }
    }
    __syncthreads();

    // ---- combine 4 partials (exact online-softmax merge), coalesced store ----
    {
        int row = tid >> 4;          // 0..15
        int hb  = tid & 15;          // 0..15
        float m0 = mlds[0][row], m1 = mlds[1][row], m2 = mlds[2][row], m3 = mlds[3][row];
        float M = fmaxf(fmaxf(m0, m1), fmaxf(m2, m3));   // finite: wave 0 always has tile 0
        float w0 = __builtin_amdgcn_exp2f(m0 - M);
        float w1 = __builtin_amdgcn_exp2f(m1 - M);
        float w2 = __builtin_amdgcn_exp2f(m2 - M);
        float w3 = __builtin_amdgcn_exp2f(m3 - M);
        float L = llds[0][row]*w0 + llds[1][row]*w1 + llds[2][row]*w2 + llds[3][row]*w3;
        float inv = 1.0f / L;
        size_t obase = ((size_t)b*SEQ + tq + row) * HDIM + hb;
#pragma unroll
        for (int j = 0; j < 4; j++){
            int h = hb + 16*j;
            float acc = olds[0][row][h]*w0 + olds[1][row][h]*w1
                      + olds[2][row][h]*w2 + olds[3][row][h]*w3;
            out[obase + 16*j] = acc * inv;
        }
    }
}

extern "C" void kernel_launch(void* const* d_in, const int* in_sizes, int n_in,
                              void* d_out, int out_size, void* d_ws, size_t ws_size,
                              hipStream_t stream) {
    (void)in_sizes; (void)n_in; (void)out_size; (void)ws_size;
    const float* x  = (const float*)d_in[0];
    const float* wq = (const float*)d_in[1];
    const float* wk = (const float*)d_in[2];
    const float* wv = (const float*)d_in[3];
    float* out = (float*)d_out;

    short* ws  = (short*)d_ws;               // ~7.1 MB total workspace
    short* wtP = ws;                          // packed W: 32*12288 shorts = 768 KB
    short* q   = wtP + (size_t)NKS*STEPSH;
    short* k   = q + (size_t)BT*HDIM;
    short* vt  = k + (size_t)BT*HDIM;

    prep_w_kernel<<<NCAT, 256, 0, stream>>>(wq, wk, wv, wtP);
    proj_kernel<<<BT/32, 256, 0, stream>>>(x, wtP, q, k, vt);
    attn_kernel<<<dim3(SEQ/16, BATCH), 256, 0, stream>>>(q, k, vt, out);
}

// Round 14
// 68.885 us; speedup vs baseline: 1.2650x; 1.2650x over previous
//
#include <hip/hip_runtime.h>

#define D_MODEL 1024
#define HDIM    64
#define BATCH   8
#define SEQ     2048
#define BT      (BATCH*SEQ)
#define NCAT    192
#define KSTEP   32
#define NKS     (D_MODEL/KSTEP)          // 32 k-steps
#define FRAGSH  512                      // shorts per frag: 64 lanes x 8
#define STEPSH  (24*FRAGSH)              // 24 frags (12 hi + 12 lo) per k-step

typedef __attribute__((ext_vector_type(8))) short s8v;
typedef __attribute__((ext_vector_type(4))) float f4;

__device__ __forceinline__ unsigned short f2bf(float f){
    unsigned u = __builtin_bit_cast(unsigned, f);
    u += 0x7fffu + ((u >> 16) & 1u);
    return (unsigned short)(u >> 16);
}
__device__ __forceinline__ float bf2f(unsigned short h){
    unsigned u = ((unsigned)h) << 16;
    return __builtin_bit_cast(float, u);
}
__device__ __forceinline__ f4 MFMA(s8v a, s8v b, f4 c){
    return __builtin_amdgcn_mfma_f32_16x16x32_bf16(a, b, c, 0, 0, 0);
}

// ---- kernel 1: W -> fragment-packed Wt (hi/lo) ----
// wtP layout: [kstep t1][frag f][lane l][e] shorts; f<12: hi of subtile nb=f,
// f>=12: lo of nb=f-12. One frag = 64 lanes x 16B, contiguous 1KB.
__global__ void prep_w_kernel(const float* __restrict__ wq, const float* __restrict__ wk,
                              const float* __restrict__ wv,
                              short* __restrict__ wtP){
    int ncat = blockIdx.x;
    const float* w = (ncat < 64) ? wq : ((ncat < 128) ? wk : wv);
    int n  = ncat & 63;
    int nb = ncat >> 4, ln = ncat & 15;
    for (int k = threadIdx.x; k < D_MODEL; k += blockDim.x){
        float f = w[k*HDIM + n];
        unsigned short h = f2bf(f);
        unsigned short l = f2bf(f - bf2f(h));
        int t1 = k >> 5, g = (k >> 3) & 3, e = k & 7;
        size_t base = (size_t)t1*STEPSH + (size_t)((g*16 + ln) << 3) + e;
        wtP[base + (size_t)nb*FRAGSH]        = (short)h;
        wtP[base + (size_t)(12 + nb)*FRAGSH] = (short)l;
    }
}

// ---- kernel 2: fused QKV projection — global_load_lds + counted-vmcnt pipeline ----
// 512 blocks x 4 waves (2 barrier domains/CU). Block tile 32 rows x 192 cols;
// wave = 32 rows x 48 cols. x staged fp32 into 4 LDS buffers, 3 steps ahead,
// via global_load_lds with PRE-SWIZZLED source (slot ^= row&7) so stride-128B
// ds_reads are conflict-free. W frags direct global->reg (L2), 2 steps ahead.
// Raw s_barrier + hand-counted vmcnt: prefetches survive across barriers.
__global__ __launch_bounds__(256) void proj_kernel(
        const float* __restrict__ x,
        const short* __restrict__ wtP,
        short* __restrict__ q, short* __restrict__ k,
        short* __restrict__ vt){
    __shared__ __align__(16) float xs[4][32][32];   // 16 KB: [buf][row][slot-XOR'd fp32]
    int tid = threadIdx.x;
    int wid = tid >> 6, lane = tid & 63, g = lane >> 4, ln = lane & 15;
    int m0 = blockIdx.x * 32;

    // staging: thread -> row sr=tid>>3, slot ss=tid&7 (16B). LDS dest is linear
    // (wave base + lane*16); source slot = ss ^ (sr&7)  => LDS[r][s] holds
    // x cols ((s^(r&7))*4 ..) — the read side applies the same XOR.
    int sr = tid >> 3, ss = tid & 7;
    const float* xsrc = x + (size_t)(m0 + sr)*D_MODEL + ((ss ^ (sr & 7)) << 2);
    const short* wb   = wtP + (size_t)(wid*3)*FRAGSH + (size_t)lane*8;

    f4 acc[6];
#pragma unroll
    for (int i = 0; i < 6; i++) acc[i] = (f4){0.f,0.f,0.f,0.f};

    s8v whA0, whA1, whA2, wlA0, wlA1, wlA2;
    s8v whB0, whB1, whB2, wlB0, wlB1, wlB2;

#define GLOADX(T) { \
    __builtin_amdgcn_global_load_lds(xsrc + (size_t)(T)*KSTEP, \
                                     &xs[(T) & 3][wid*8][0], 16, 0, 0); }

#define LOADW(P, T) { \
    const short* wp = wb + (size_t)(T)*STEPSH; \
    wh##P##0 = *(const s8v*)(wp); \
    wh##P##1 = *(const s8v*)(wp + FRAGSH); \
    wh##P##2 = *(const s8v*)(wp + 2*FRAGSH); \
    wl##P##0 = *(const s8v*)(wp + 12*FRAGSH); \
    wl##P##1 = *(const s8v*)(wp + 13*FRAGSH); \
    wl##P##2 = *(const s8v*)(wp + 14*FRAGSH); }

#define CVT8(DST, VA, VB) { \
    DST[0] = (short)f2bf(VA.x); DST[1] = (short)f2bf(VA.y); \
    DST[2] = (short)f2bf(VA.z); DST[3] = (short)f2bf(VA.w); \
    DST[4] = (short)f2bf(VB.x); DST[5] = (short)f2bf(VB.y); \
    DST[6] = (short)f2bf(VB.z); DST[7] = (short)f2bf(VB.w); }

#define MFMAS(P, A0, A1) { \
    acc[0] = MFMA(A0, wh##P##0, acc[0]); acc[0] = MFMA(A0, wl##P##0, acc[0]); \
    acc[1] = MFMA(A0, wh##P##1, acc[1]); acc[1] = MFMA(A0, wl##P##1, acc[1]); \
    acc[2] = MFMA(A0, wh##P##2, acc[2]); acc[2] = MFMA(A0, wl##P##2, acc[2]); \
    acc[3] = MFMA(A1, wh##P##0, acc[3]); acc[3] = MFMA(A1, wl##P##0, acc[3]); \
    acc[4] = MFMA(A1, wh##P##1, acc[4]); acc[4] = MFMA(A1, wl##P##1, acc[4]); \
    acc[5] = MFMA(A1, wh##P##2, acc[5]); acc[5] = MFMA(A1, wl##P##2, acc[5]); }

// One k-step. vmcnt(VM) guarantees X(T) staged (X issued LAST each step; in-order
// completion => "all but VM newest done"). Barrier publishes it across waves.
// sched_barrier(0) pins: (a) no ds_read hoisted above the barrier, (b) the
// gload_lds stays the last VMEM of the step (keeps the vmcnt ledger exact).
#define STEP(P, T, VM) { \
    asm volatile("s_waitcnt vmcnt(" #VM ")" ::: "memory"); \
    __builtin_amdgcn_s_barrier(); \
    __builtin_amdgcn_sched_barrier(0); \
    int bq = (T) & 3, r7 = ln & 7; \
    float4 xa = *(const float4*)&xs[bq][ln]     [((2*g)   ^ r7) << 2]; \
    float4 xb = *(const float4*)&xs[bq][ln]     [((2*g+1) ^ r7) << 2]; \
    float4 xc = *(const float4*)&xs[bq][ln + 16][((2*g)   ^ r7) << 2]; \
    float4 xd = *(const float4*)&xs[bq][ln + 16][((2*g+1) ^ r7) << 2]; \
    s8v A0, A1; \
    CVT8(A0, xa, xb) \
    CVT8(A1, xc, xd) \
    MFMAS(P, A0, A1) \
    if ((T) + 2 < NKS) LOADW(P, (T) + 2) \
    __builtin_amdgcn_sched_barrier(0); \
    if ((T) + 3 < NKS) GLOADX((T) + 3) \
    __builtin_amdgcn_sched_barrier(0); \
}

    // prologue: X0..X2 in the DMA queue (X first => vmcnt ledger), then W0,W1
    GLOADX(0)
    GLOADX(1)
    GLOADX(2)
    __builtin_amdgcn_sched_barrier(0);
    LOADW(A, 0)
    LOADW(B, 1)

    for (int t = 0; t < 30; t += 2){
        STEP(A, t,     14)
        STEP(B, t + 1, 14)
    }
    STEP(A, 30, 13)
    STEP(B, 31, 6)
#undef GLOADX
#undef LOADW
#undef CVT8
#undef MFMAS
#undef STEP

    // epilogue: q,k,v single bf16 (GEMM was x_bf16 * W_fp32-accurate)
#pragma unroll
    for (int rf = 0; rf < 2; rf++){
#pragma unroll
        for (int nb = 0; nb < 3; nb++){
            int ncat = wid*48 + nb*16 + ln;
            int mat = ncat >> 6, h = ncat & 63;
#pragma unroll
            for (int r = 0; r < 4; r++){
                size_t trow = (size_t)m0 + rf*16 + g*4 + r;
                float v = acc[rf*3 + nb][r];
                unsigned short hh = f2bf(v);
                if (mat == 0){
                    q[trow*HDIM + h] = (short)hh;
                } else if (mat == 1){
                    k[trow*HDIM + h] = (short)hh;
                } else {
                    size_t bb = trow >> 11, t2 = trow & 2047;
                    vt[((bb*HDIM + h) << 11) + t2] = (short)hh;
                }
            }
        }
    }
}

// ---- kernel 3: causal flash attention, in-block KV-split, KVBLK=64 ----
// Single-bf16 Q/K; wave w owns KV tiles w, w+4, ...; partials merged in LDS
// at block end (exact algebra). qi swizzle balances per-CU work.
__global__ __launch_bounds__(256, 5) void attn_kernel(
        const short* __restrict__ qg, const short* __restrict__ kg,
        const short* __restrict__ vt, float* __restrict__ out){
    __shared__ unsigned short plds[4][16][112];
    __shared__ float olds[4][16][65];
    __shared__ float mlds[4][16], llds[4][16];
    const float SC = 0.125f * 1.44269504088896340736f;  // 1/sqrt(64) * log2(e)
    int tid = threadIdx.x;
    int w = tid >> 6, lane = tid & 63, g = lane >> 4, ln = lane & 15;
    int b = blockIdx.y;
    int qi = ((blockIdx.y >> 1) & 1) ? (int)(gridDim.x - 1 - blockIdx.x) : (int)blockIdx.x;
    int tq = qi * 16;

    size_t qoff = ((size_t)b*SEQ + tq + ln) * HDIM + g*8;
    s8v q0 = *(const s8v*)(qg + qoff);
    s8v q1 = *(const s8v*)(qg + qoff + 32);

    f4 o0 = {0.f,0.f,0.f,0.f}, o1 = o0, o2 = o0, o3 = o0;
    float m[4], lsum[4];
#pragma unroll
    for (int r = 0; r < 4; r++){ m[r] = -__builtin_inff(); lsum[r] = 0.f; }

    int ntiles = (tq + 79) >> 6;   // ceil((tq+16)/64)
    for (int ti = w; ti < ntiles; ti += 4){
        int s0 = ti << 6;
        size_t kbase = ((size_t)b*SEQ + s0 + ln) * HDIM + g*8;
        f4 z0, z1, z2, z3;
#define QK_SUBTILE(ZJ, J) { \
        const short* kp = kg + kbase + (J)*16*HDIM; \
        s8v k0 = *(const s8v*)(kp); \
        s8v k1 = *(const s8v*)(kp + 32); \
        f4 s = {0.f,0.f,0.f,0.f}; \
        s = MFMA(q0, k0, s); s = MFMA(q1, k1, s); \
        ZJ[0] = s[0]*SC; ZJ[1] = s[1]*SC; ZJ[2] = s[2]*SC; ZJ[3] = s[3]*SC; }
        QK_SUBTILE(z0, 0)
        QK_SUBTILE(z1, 1)
        QK_SUBTILE(z2, 2)
        QK_SUBTILE(z3, 3)
#undef QK_SUBTILE
        if (s0 + 63 > tq){   // causal mask (near-diagonal tiles only)
#pragma unroll
            for (int r = 0; r < 4; r++){
                int t = tq + g*4 + r;
                if (s0      + ln > t) z0[r] = -__builtin_inff();
                if (s0 + 16 + ln > t) z1[r] = -__builtin_inff();
                if (s0 + 32 + ln > t) z2[r] = -__builtin_inff();
                if (s0 + 48 + ln > t) z3[r] = -__builtin_inff();
            }
        }
        float al[4];
#pragma unroll
        for (int r = 0; r < 4; r++){
            float v = fmaxf(fmaxf(z0[r], z1[r]), fmaxf(z2[r], z3[r]));
            v = fmaxf(v, __shfl_xor(v, 1));
            v = fmaxf(v, __shfl_xor(v, 2));
            v = fmaxf(v, __shfl_xor(v, 4));
            v = fmaxf(v, __shfl_xor(v, 8));
            float mn = fmaxf(m[r], v);
            al[r] = __builtin_amdgcn_exp2f(m[r] - mn);
            float p0 = __builtin_amdgcn_exp2f(z0[r] - mn);
            float p1 = __builtin_amdgcn_exp2f(z1[r] - mn);
            float p2 = __builtin_amdgcn_exp2f(z2[r] - mn);
            float p3 = __builtin_amdgcn_exp2f(z3[r] - mn);
            lsum[r] = lsum[r]*al[r] + ((p0 + p1) + (p2 + p3));  // lane-partial
            m[r] = mn;
            int row = g*4 + r;
            plds[w][row][ln]      = f2bf(p0);
            plds[w][row][ln + 16] = f2bf(p1);
            plds[w][row][ln + 32] = f2bf(p2);
            plds[w][row][ln + 48] = f2bf(p3);
        }
#pragma unroll
        for (int r = 0; r < 4; r++){
            o0[r] *= al[r]; o1[r] *= al[r]; o2[r] *= al[r]; o3[r] *= al[r];
        }
        asm volatile("s_waitcnt lgkmcnt(0)" ::: "memory");  // cross-lane P write->read
        __builtin_amdgcn_sched_barrier(0);
        s8v pa0 = *(const s8v*)&plds[w][ln][g*8];
        s8v pa1 = *(const s8v*)&plds[w][ln][32 + g*8];
        size_t voff = ((size_t)b*HDIM + ln) * SEQ + s0 + g*8;
        s8v v00 = *(const s8v*)(vt + voff);
        s8v v01 = *(const s8v*)(vt + voff + 32);
        s8v v10 = *(const s8v*)(vt + voff + 16*SEQ);
        s8v v11 = *(const s8v*)(vt + voff + 16*SEQ + 32);
        s8v v20 = *(const s8v*)(vt + voff + 32*SEQ);
        s8v v21 = *(const s8v*)(vt + voff + 32*SEQ + 32);
        s8v v30 = *(const s8v*)(vt + voff + 48*SEQ);
        s8v v31 = *(const s8v*)(vt + voff + 48*SEQ + 32);
        o0 = MFMA(pa0, v00, o0); o0 = MFMA(pa1, v01, o0);
        o1 = MFMA(pa0, v10, o1); o1 = MFMA(pa1, v11, o1);
        o2 = MFMA(pa0, v20, o2); o2 = MFMA(pa1, v21, o2);
        o3 = MFMA(pa0, v30, o3); o3 = MFMA(pa1, v31, o3);
    }

    // deferred l-sum reduce (off the per-tile critical path)
#pragma unroll
    for (int r = 0; r < 4; r++){
        float s = lsum[r];
        s += __shfl_xor(s, 1);
        s += __shfl_xor(s, 2);
        s += __shfl_xor(s, 4);
        s += __shfl_xor(s, 8);
        lsum[r] = s;
    }

    // ---- write per-wave partials to LDS ----
#pragma unroll
    for (int r = 0; r < 4; r++){
        int row = g*4 + r;
        olds[w][row][ln]      = o0[r];
        olds[w][row][ln + 16] = o1[r];
        olds[w][row][ln + 32] = o2[r];
        olds[w][row][ln + 48] = o3[r];
        if (ln == 0){ mlds[w][row] = m[r]; llds[w][row] = lsum[r]; }
    }
    __syncthreads();

    // ---- combine 4 partials (exact online-softmax merge), coalesced store ----
    {
        int row = tid >> 4;          // 0..15
        int hb  = tid & 15;          // 0..15
        float m0 = mlds[0][row], m1 = mlds[1][row], m2 = mlds[2][row], m3 = mlds[3][row];
        float M = fmaxf(fmaxf(m0, m1), fmaxf(m2, m3));   // finite: wave 0 always has tile 0
        float w0 = __builtin_amdgcn_exp2f(m0 - M);
        float w1 = __builtin_amdgcn_exp2f(m1 - M);
        float w2 = __builtin_amdgcn_exp2f(m2 - M);
        float w3 = __builtin_amdgcn_exp2f(m3 - M);
        float L = llds[0][row]*w0 + llds[1][row]*w1 + llds[2][row]*w2 + llds[3][row]*w3;
        float inv = 1.0f / L;
        size_t obase = ((size_t)b*SEQ + tq + row) * HDIM + hb;
#pragma unroll
        for (int j = 0; j < 4; j++){
            int h = hb + 16*j;
            float acc = olds[0][row][h]*w0 + olds[1][row][h]*w1
                      + olds[2][row][h]*w2 + olds[3][row][h]*w3;
            out[obase + 16*j] = acc * inv;
        }
    }
}

extern "C" void kernel_launch(void* const* d_in, const int* in_sizes, int n_in,
                              void* d_out, int out_size, void* d_ws, size_t ws_size,
                              hipStream_t stream) {
    (void)in_sizes; (void)n_in; (void)out_size; (void)ws_size;
    const float* x  = (const float*)d_in[0];
    const float* wq = (const float*)d_in[1];
    const float* wk = (const float*)d_in[2];
    const float* wv = (const float*)d_in[3];
    float* out = (float*)d_out;

    short* ws  = (short*)d_ws;               // ~7.1 MB total workspace
    short* wtP = ws;                          // packed W: 32*12288 shorts = 768 KB
    short* q   = wtP + (size_t)NKS*STEPSH;
    short* k   = q + (size_t)BT*HDIM;
    short* vt  = k + (size_t)BT*HDIM;

    prep_w_kernel<<<NCAT, 256, 0, stream>>>(wq, wk, wv, wtP);
    proj_kernel<<<BT/32, 256, 0, stream>>>(x, wtP, q, k, vt);
    attn_kernel<<<dim3(SEQ/16, BATCH), 256, 0, stream>>>(q, k, vt, out);
}

// Round 15
// 61.263 us; speedup vs baseline: 1.4224x; 1.1244x over previous
//
#include <hip/hip_runtime.h>

#define D_MODEL 1024
#define HDIM    64
#define BATCH   8
#define SEQ     2048
#define BT      (BATCH*SEQ)
#define NCAT    192
#define BM      64
#define BK      64
#define NSTEP   16                       // 1024/64
#define WFRAG   512                      // shorts per frag: 64 lanes x 8
#define WSTEP32 (12*WFRAG)               // 12 hi frags per 32-k step

typedef __attribute__((ext_vector_type(8))) short s8v;
typedef __attribute__((ext_vector_type(4))) float f4;

__device__ __forceinline__ unsigned short f2bf(float f){
    unsigned u = __builtin_bit_cast(unsigned, f);
    u += 0x7fffu + ((u >> 16) & 1u);
    return (unsigned short)(u >> 16);
}
__device__ __forceinline__ float bf2f(unsigned short h){
    unsigned u = ((unsigned)h) << 16;
    return __builtin_bit_cast(float, u);
}
__device__ __forceinline__ f4 MFMA(s8v a, s8v b, f4 c){
    return __builtin_amdgcn_mfma_f32_16x16x32_bf16(a, b, c, 0, 0, 0);
}

// ---- kernel 1: W -> fragment-packed Wt (hi only) ----
// wtP: [k32-step t1][frag nb(12)][lane(64)][e(8)] shorts; frag = contiguous 1KB.
// Element (k, ncat): t1=k>>5, lane=((k>>3)&3)*16 + (ncat&15), e=k&7, nb=ncat>>4.
__global__ void prep_w_kernel(const float* __restrict__ wq, const float* __restrict__ wk,
                              const float* __restrict__ wv,
                              short* __restrict__ wtP){
    int ncat = blockIdx.x;
    const float* w = (ncat < 64) ? wq : ((ncat < 128) ? wk : wv);
    int n  = ncat & 63;
    int nb = ncat >> 4, ln = ncat & 15;
    for (int k = threadIdx.x; k < D_MODEL; k += blockDim.x){
        float f = w[k*HDIM + n];
        int t1 = k >> 5, g = (k >> 3) & 3, e = k & 7;
        wtP[(size_t)t1*WSTEP32 + (size_t)nb*WFRAG + ((g*16 + ln) << 3) + e]
            = (short)f2bf(f);
    }
}

// ---- kernel 2: fused QKV projection — BM=64/BK=64, counted-vmcnt pipeline ----
// 256 blocks x 8 waves (1 block/CU). Wave tile 32 rows x 48 cols.
// X: fp32 -> LDS via global_load_lds, 4 buffers, 2 steps ahead, slot-XOR swizzle
//    (slot' = (s&8)|((s&7)^(row&7)), involution; read applies same XOR).
// W: hi-only frags, direct global->reg, 2-step double buffer (A/B).
// Ledger: per step issue [6x W(t+2), 2x X(t+2)] -> top-of-step vmcnt(8) waits
// exactly X(t) (oldest 8 = W(t)+X(t)); t=15 drains with vmcnt(0).
__global__ __launch_bounds__(512) void proj_kernel(
        const float* __restrict__ x,
        const short* __restrict__ wtP,
        short* __restrict__ q, short* __restrict__ k,
        short* __restrict__ vt){
    __shared__ __align__(16) float xs[4][64][64];   // 64 KB
    int tid = threadIdx.x;
    int wid = tid >> 6, lane = tid & 63, g = lane >> 4, ln = lane & 15;
    int wm = wid >> 2, wn = wid & 3;   // wave: rows wm*32..+31, cols wn*48..+47
    int m0 = blockIdx.x * BM;

    // gload: wave wid stages rows 8w..8w+3 (call A) and 8w+4..8w+7 (call B);
    // lane l -> row r0+(l>>4), 16B-slot l&15; source slot pre-swizzled.
    int rowA = wid*8 + (lane >> 4);
    int rowB = rowA + 4;
    int sl   = lane & 15;
    int swzA = (sl & 8) | ((sl & 7) ^ (rowA & 7));
    int swzB = (sl & 8) | ((sl & 7) ^ (rowB & 7));
    const float* xsrcA = x + (size_t)(m0 + rowA)*D_MODEL + swzA*4;
    const float* xsrcB = x + (size_t)(m0 + rowB)*D_MODEL + swzB*4;
    const short* wb    = wtP + (size_t)(wn*3)*WFRAG + (size_t)lane*8;

    f4 acc[6];
#pragma unroll
    for (int i = 0; i < 6; i++) acc[i] = (f4){0.f,0.f,0.f,0.f};

    s8v wA0, wA1, wA2, wA3, wA4, wA5;
    s8v wB0, wB1, wB2, wB3, wB4, wB5;

#define GLOADX(T) { \
    __builtin_amdgcn_global_load_lds(xsrcA + (size_t)(T)*BK, \
                                     &xs[(T) & 3][wid*8][0], 16, 0, 0); \
    __builtin_amdgcn_global_load_lds(xsrcB + (size_t)(T)*BK, \
                                     &xs[(T) & 3][wid*8 + 4][0], 16, 0, 0); }

#define LOADW(P, T) { \
    const short* wp = wb + (size_t)(2*(T))*WSTEP32; \
    w##P##0 = *(const s8v*)(wp); \
    w##P##1 = *(const s8v*)(wp + WFRAG); \
    w##P##2 = *(const s8v*)(wp + 2*WFRAG); \
    w##P##3 = *(const s8v*)(wp + WSTEP32); \
    w##P##4 = *(const s8v*)(wp + WSTEP32 + WFRAG); \
    w##P##5 = *(const s8v*)(wp + WSTEP32 + 2*WFRAG); }

#define CVT8(DST, VA, VB) { \
    DST[0] = (short)f2bf(VA.x); DST[1] = (short)f2bf(VA.y); \
    DST[2] = (short)f2bf(VA.z); DST[3] = (short)f2bf(VA.w); \
    DST[4] = (short)f2bf(VB.x); DST[5] = (short)f2bf(VB.y); \
    DST[6] = (short)f2bf(VB.z); DST[7] = (short)f2bf(VB.w); }

// One k-step (BK=64 = two 16x16x32 k-subtiles). vmcnt(VM) then barrier:
// each wave waits its own X(T) slices, barrier publishes all slices.
#define STEP(P, T, VM) { \
    asm volatile("s_waitcnt vmcnt(" #VM ")" ::: "memory"); \
    __builtin_amdgcn_s_barrier(); \
    __builtin_amdgcn_sched_barrier(0); \
    int bq = (T) & 3, r7 = ln & 7; \
    int r0 = wm*32 + ln, r1 = r0 + 16; \
    float4 xa = *(const float4*)&xs[bq][r0][(((2*g)   ^ r7)) << 2]; \
    float4 xb = *(const float4*)&xs[bq][r0][(((2*g+1) ^ r7)) << 2]; \
    float4 xc = *(const float4*)&xs[bq][r1][(((2*g)   ^ r7)) << 2]; \
    float4 xd = *(const float4*)&xs[bq][r1][(((2*g+1) ^ r7)) << 2]; \
    float4 xe = *(const float4*)&xs[bq][r0][((8 | ((2*g)   ^ r7))) << 2]; \
    float4 xf = *(const float4*)&xs[bq][r0][((8 | ((2*g+1) ^ r7))) << 2]; \
    float4 xg = *(const float4*)&xs[bq][r1][((8 | ((2*g)   ^ r7))) << 2]; \
    float4 xh = *(const float4*)&xs[bq][r1][((8 | ((2*g+1) ^ r7))) << 2]; \
    s8v A00, A10, A01, A11; \
    CVT8(A00, xa, xb) \
    CVT8(A10, xc, xd) \
    CVT8(A01, xe, xf) \
    CVT8(A11, xg, xh) \
    acc[0] = MFMA(A00, w##P##0, acc[0]); \
    acc[1] = MFMA(A00, w##P##1, acc[1]); \
    acc[2] = MFMA(A00, w##P##2, acc[2]); \
    acc[3] = MFMA(A10, w##P##0, acc[3]); \
    acc[4] = MFMA(A10, w##P##1, acc[4]); \
    acc[5] = MFMA(A10, w##P##2, acc[5]); \
    acc[0] = MFMA(A01, w##P##3, acc[0]); \
    acc[1] = MFMA(A01, w##P##4, acc[1]); \
    acc[2] = MFMA(A01, w##P##5, acc[2]); \
    acc[3] = MFMA(A11, w##P##3, acc[3]); \
    acc[4] = MFMA(A11, w##P##4, acc[4]); \
    acc[5] = MFMA(A11, w##P##5, acc[5]); \
    __builtin_amdgcn_sched_barrier(0); \
    if ((T) + 2 < NSTEP) LOADW(P, (T) + 2) \
    __builtin_amdgcn_sched_barrier(0); \
    if ((T) + 2 < NSTEP) GLOADX((T) + 2) \
    __builtin_amdgcn_sched_barrier(0); \
}

    // prologue — order matters for the vmcnt ledger: W0, X0, W1, X1
    LOADW(A, 0)
    __builtin_amdgcn_sched_barrier(0);
    GLOADX(0)
    __builtin_amdgcn_sched_barrier(0);
    LOADW(B, 1)
    __builtin_amdgcn_sched_barrier(0);
    GLOADX(1)
    __builtin_amdgcn_sched_barrier(0);

    for (int t = 0; t < 14; t += 2){
        STEP(A, t,     8)
        STEP(B, t + 1, 8)
    }
    STEP(A, 14, 8)
    STEP(B, 15, 0)
#undef GLOADX
#undef LOADW
#undef CVT8
#undef STEP

    // epilogue: q,k,v single bf16 (v transposed [B][64][T])
#pragma unroll
    for (int rf = 0; rf < 2; rf++){
#pragma unroll
        for (int nb = 0; nb < 3; nb++){
            int ncat = wn*48 + nb*16 + ln;
            int mat = ncat >> 6, h = ncat & 63;
#pragma unroll
            for (int r = 0; r < 4; r++){
                size_t trow = (size_t)m0 + wm*32 + rf*16 + g*4 + r;
                float v = acc[rf*3 + nb][r];
                unsigned short hh = f2bf(v);
                if (mat == 0){
                    q[trow*HDIM + h] = (short)hh;
                } else if (mat == 1){
                    k[trow*HDIM + h] = (short)hh;
                } else {
                    size_t bb = trow >> 11, t2 = trow & 2047;
                    vt[((bb*HDIM + h) << 11) + t2] = (short)hh;
                }
            }
        }
    }
}

// ---- kernel 3: causal flash attention, in-block KV-split, KVBLK=64 ----
// Single-bf16 Q/K; wave w owns KV tiles w, w+4, ...; partials merged in LDS
// at block end (exact algebra). qi swizzle balances per-CU work.
__global__ __launch_bounds__(256, 5) void attn_kernel(
        const short* __restrict__ qg, const short* __restrict__ kg,
        const short* __restrict__ vt, float* __restrict__ out){
    __shared__ unsigned short plds[4][16][112];
    __shared__ float olds[4][16][65];
    __shared__ float mlds[4][16], llds[4][16];
    const float SC = 0.125f * 1.44269504088896340736f;  // 1/sqrt(64) * log2(e)
    int tid = threadIdx.x;
    int w = tid >> 6, lane = tid & 63, g = lane >> 4, ln = lane & 15;
    int b = blockIdx.y;
    int qi = ((blockIdx.y >> 1) & 1) ? (int)(gridDim.x - 1 - blockIdx.x) : (int)blockIdx.x;
    int tq = qi * 16;

    size_t qoff = ((size_t)b*SEQ + tq + ln) * HDIM + g*8;
    s8v q0 = *(const s8v*)(qg + qoff);
    s8v q1 = *(const s8v*)(qg + qoff + 32);

    f4 o0 = {0.f,0.f,0.f,0.f}, o1 = o0, o2 = o0, o3 = o0;
    float m[4], lsum[4];
#pragma unroll
    for (int r = 0; r < 4; r++){ m[r] = -__builtin_inff(); lsum[r] = 0.f; }

    int ntiles = (tq + 79) >> 6;   // ceil((tq+16)/64)
    for (int ti = w; ti < ntiles; ti += 4){
        int s0 = ti << 6;
        size_t kbase = ((size_t)b*SEQ + s0 + ln) * HDIM + g*8;
        f4 z0, z1, z2, z3;
#define QK_SUBTILE(ZJ, J) { \
        const short* kp = kg + kbase + (J)*16*HDIM; \
        s8v k0 = *(const s8v*)(kp); \
        s8v k1 = *(const s8v*)(kp + 32); \
        f4 s = {0.f,0.f,0.f,0.f}; \
        s = MFMA(q0, k0, s); s = MFMA(q1, k1, s); \
        ZJ[0] = s[0]*SC; ZJ[1] = s[1]*SC; ZJ[2] = s[2]*SC; ZJ[3] = s[3]*SC; }
        QK_SUBTILE(z0, 0)
        QK_SUBTILE(z1, 1)
        QK_SUBTILE(z2, 2)
        QK_SUBTILE(z3, 3)
#undef QK_SUBTILE
        if (s0 + 63 > tq){   // causal mask (near-diagonal tiles only)
#pragma unroll
            for (int r = 0; r < 4; r++){
                int t = tq + g*4 + r;
                if (s0      + ln > t) z0[r] = -__builtin_inff();
                if (s0 + 16 + ln > t) z1[r] = -__builtin_inff();
                if (s0 + 32 + ln > t) z2[r] = -__builtin_inff();
                if (s0 + 48 + ln > t) z3[r] = -__builtin_inff();
            }
        }
        float al[4];
#pragma unroll
        for (int r = 0; r < 4; r++){
            float v = fmaxf(fmaxf(z0[r], z1[r]), fmaxf(z2[r], z3[r]));
            v = fmaxf(v, __shfl_xor(v, 1));
            v = fmaxf(v, __shfl_xor(v, 2));
            v = fmaxf(v, __shfl_xor(v, 4));
            v = fmaxf(v, __shfl_xor(v, 8));
            float mn = fmaxf(m[r], v);
            al[r] = __builtin_amdgcn_exp2f(m[r] - mn);
            float p0 = __builtin_amdgcn_exp2f(z0[r] - mn);
            float p1 = __builtin_amdgcn_exp2f(z1[r] - mn);
            float p2 = __builtin_amdgcn_exp2f(z2[r] - mn);
            float p3 = __builtin_amdgcn_exp2f(z3[r] - mn);
            lsum[r] = lsum[r]*al[r] + ((p0 + p1) + (p2 + p3));  // lane-partial
            m[r] = mn;
            int row = g*4 + r;
            plds[w][row][ln]      = f2bf(p0);
            plds[w][row][ln + 16] = f2bf(p1);
            plds[w][row][ln + 32] = f2bf(p2);
            plds[w][row][ln + 48] = f2bf(p3);
        }
#pragma unroll
        for (int r = 0; r < 4; r++){
            o0[r] *= al[r]; o1[r] *= al[r]; o2[r] *= al[r]; o3[r] *= al[r];
        }
        asm volatile("s_waitcnt lgkmcnt(0)" ::: "memory");  // cross-lane P write->read
        __builtin_amdgcn_sched_barrier(0);
        s8v pa0 = *(const s8v*)&plds[w][ln][g*8];
        s8v pa1 = *(const s8v*)&plds[w][ln][32 + g*8];
        size_t voff = ((size_t)b*HDIM + ln) * SEQ + s0 + g*8;
        s8v v00 = *(const s8v*)(vt + voff);
        s8v v01 = *(const s8v*)(vt + voff + 32);
        s8v v10 = *(const s8v*)(vt + voff + 16*SEQ);
        s8v v11 = *(const s8v*)(vt + voff + 16*SEQ + 32);
        s8v v20 = *(const s8v*)(vt + voff + 32*SEQ);
        s8v v21 = *(const s8v*)(vt + voff + 32*SEQ + 32);
        s8v v30 = *(const s8v*)(vt + voff + 48*SEQ);
        s8v v31 = *(const s8v*)(vt + voff + 48*SEQ + 32);
        o0 = MFMA(pa0, v00, o0); o0 = MFMA(pa1, v01, o0);
        o1 = MFMA(pa0, v10, o1); o1 = MFMA(pa1, v11, o1);
        o2 = MFMA(pa0, v20, o2); o2 = MFMA(pa1, v21, o2);
        o3 = MFMA(pa0, v30, o3); o3 = MFMA(pa1, v31, o3);
    }

    // deferred l-sum reduce (off the per-tile critical path)
#pragma unroll
    for (int r = 0; r < 4; r++){
        float s = lsum[r];
        s += __shfl_xor(s, 1);
        s += __shfl_xor(s, 2);
        s += __shfl_xor(s, 4);
        s += __shfl_xor(s, 8);
        lsum[r] = s;
    }

    // ---- write per-wave partials to LDS ----
#pragma unroll
    for (int r = 0; r < 4; r++){
        int row = g*4 + r;
        olds[w][row][ln]      = o0[r];
        olds[w][row][ln + 16] = o1[r];
        olds[w][row][ln + 32] = o2[r];
        olds[w][row][ln + 48] = o3[r];
        if (ln == 0){ mlds[w][row] = m[r]; llds[w][row] = lsum[r]; }
    }
    __syncthreads();

    // ---- combine 4 partials (exact online-softmax merge), coalesced store ----
    {
        int row = tid >> 4;          // 0..15
        int hb  = tid & 15;          // 0..15
        float m0 = mlds[0][row], m1 = mlds[1][row], m2 = mlds[2][row], m3 = mlds[3][row];
        float M = fmaxf(fmaxf(m0, m1), fmaxf(m2, m3));   // finite: wave 0 always has tile 0
        float w0 = __builtin_amdgcn_exp2f(m0 - M);
        float w1 = __builtin_amdgcn_exp2f(m1 - M);
        float w2 = __builtin_amdgcn_exp2f(m2 - M);
        float w3 = __builtin_amdgcn_exp2f(m3 - M);
        float L = llds[0][row]*w0 + llds[1][row]*w1 + llds[2][row]*w2 + llds[3][row]*w3;
        float inv = 1.0f / L;
        size_t obase = ((size_t)b*SEQ + tq + row) * HDIM + hb;
#pragma unroll
        for (int j = 0; j < 4; j++){
            int h = hb + 16*j;
            float acc = olds[0][row][h]*w0 + olds[1][row][h]*w1
                      + olds[2][row][h]*w2 + olds[3][row][h]*w3;
            out[obase + 16*j] = acc * inv;
        }
    }
}

extern "C" void kernel_launch(void* const* d_in, const int* in_sizes, int n_in,
                              void* d_out, int out_size, void* d_ws, size_t ws_size,
                              hipStream_t stream) {
    (void)in_sizes; (void)n_in; (void)out_size; (void)ws_size;
    const float* x  = (const float*)d_in[0];
    const float* wq = (const float*)d_in[1];
    const float* wk = (const float*)d_in[2];
    const float* wv = (const float*)d_in[3];
    float* out = (float*)d_out;

    short* ws  = (short*)d_ws;               // ~6.4 MB total workspace
    short* wtP = ws;                          // packed W hi-only: 384 KB
    short* q   = wtP + (size_t)32*WSTEP32;
    short* k   = q + (size_t)BT*HDIM;
    short* vt  = k + (size_t)BT*HDIM;

    prep_w_kernel<<<NCAT, 256, 0, stream>>>(wq, wk, wv, wtP);
    proj_kernel<<<BT/BM, 512, 0, stream>>>(x, wtP, q, k, vt);
    attn_kernel<<<dim3(SEQ/16, BATCH), 256, 0, stream>>>(q, k, vt, out);
}